// Round 7
// baseline (541.707 us; speedup 1.0000x reference)
//
#include <hip/hip_runtime.h>

typedef unsigned short u16;
typedef unsigned int u32;
typedef float f32x4 __attribute__((ext_vector_type(4)));
typedef float f32x16 __attribute__((ext_vector_type(16)));
typedef __bf16 bf16x8 __attribute__((ext_vector_type(8)));

#define DEV static __device__ __forceinline__

DEV u16 f2bf(float f) {
  u32 u = __builtin_bit_cast(u32, f);
  u += 0x7fffu + ((u >> 16) & 1u);
  return (u16)(u >> 16);
}

DEV void gload_lds16(const void* g, void* l) {
  __builtin_amdgcn_global_load_lds(
      (const __attribute__((address_space(1))) u32*)g,
      (__attribute__((address_space(3))) u32*)l, 16, 0, 0);
}

// ---------------- convert kernels ----------------

__global__ __launch_bounds__(256) void cvt_bf16(const float* __restrict__ in,
                                                u16* __restrict__ out, int n4) {
  int i = blockIdx.x * 256 + threadIdx.x;
  const int stride = gridDim.x * 256;
  for (; i < n4; i += stride) {
    const float4 v = ((const float4*)in)[i];
    ushort4 o;
    o.x = f2bf(v.x); o.y = f2bf(v.y); o.z = f2bf(v.z); o.w = f2bf(v.w);
    ((ushort4*)out)[i] = o;
  }
}

// in [K,N] fp32 -> out [N,K] bf16 (transposed)
__global__ __launch_bounds__(256) void cvtT_bf16(const float* __restrict__ in,
                                                 u16* __restrict__ out, int K, int N) {
  int i = blockIdx.x * 256 + threadIdx.x;
  if (i >= N * K) return;
  int n = i / K, k = i - n * K;
  out[i] = f2bf(in[(long)k * N + n]);
}

// biasM[h][p] = bias_table[rel_idx[p]*12 + h], p < 2401
__global__ __launch_bounds__(256) void bias_pre(const float* __restrict__ bias_table,
                                                const int* __restrict__ rel_idx,
                                                float* __restrict__ biasM) {
  int i = blockIdx.x * 256 + threadIdx.x;
  if (i >= 12 * 2401) return;
  int h = i / 2401, p = i - h * 2401;
  biasM[i] = bias_table[rel_idx[p] * 12 + h];
}

// ---------------- 256x256 deep-pipelined GEMM (32x32x16 MFMA) ----------------
// LDS layout (per 32KB buffer): A = 128 lines x 128B (2 m-rows/line), B at +16384.
// Swizzle: (row, 16B-block b in 0..3) -> line = row>>1, slot = (row&1)*4+b,
// slot' = slot ^ (line&7). Conflict-free for BOTH stage and 32x32 frag reads
// (each 8-lane phase covers all 8 bank-quads; SQ_LDS_BANK_CONFLICT==0 measured).
// Schedule: identical to the passing r5/r6 kernel (depth-3 staging, vmcnt(4),
// one barrier per K-tile, register ping-pong X/Y). Only the MFMA shape changed.
template <bool OUT_BF16>
__global__ __launch_bounds__(512, 2) void gemm256(
    const u16* __restrict__ A, const u16* __restrict__ BT,
    void* __restrict__ C, const float* __restrict__ bias,
    int M, int N, int K, int nbn) {
  __shared__ alignas(16) char lds[131072];
  const int t = threadIdx.x;
  const int w = t >> 6, l = t & 63;
  const int wr = w >> 2, wc = w & 3;
  const int la = l & 31, cg = l >> 5;

  // bijective XCD-chunked swizzle
  const int nwg = gridDim.x;
  const int q = nwg >> 3, r = nwg & 7;
  const int xcd = blockIdx.x & 7, lid = blockIdx.x >> 3;
  const int swz = (xcd < r ? xcd * (q + 1) : r * (q + 1) + (xcd - r) * q) + lid;
  const int bm = swz / nbn, bn = swz % nbn;

  const int T = K >> 5;  // K-tiles of 32 (K=768 -> 24, even)
  const long Kb = (long)K * 2;

  // staging source (inverse swizzle; global_load_lds dest is linear) — unchanged
  const int unswz = (l & 7) ^ (l >> 3);
  const int arow = 2 * (l >> 3) + (unswz >> 2);
  const int acolb = (unswz & 3) << 4;
  const char* gA0 = (const char*)A + (long)(bm * 256 + w * 32 + arow) * Kb + acolb;
  const char* gA1 = gA0 + 16 * Kb;
  const char* gB0 = (const char*)BT + (long)(bn * 256 + w * 32 + arow) * Kb + acolb;
  const char* gB1 = gB0 + 16 * Kb;
  const int ldA0 = w * 2048, ldA1 = w * 2048 + 1024;
  const int ldB0 = 16384 + w * 2048, ldB1 = 16384 + w * 2048 + 1024;

#define STAGE(tt)                               \
  {                                             \
    const int bb = ((tt) & 3) * 32768;          \
    const long ko = (long)(tt) * 64;            \
    gload_lds16(gA0 + ko, lds + bb + ldA0);     \
    gload_lds16(gA1 + ko, lds + bb + ldA1);     \
    gload_lds16(gB0 + ko, lds + bb + ldB0);     \
    gload_lds16(gB1 + ko, lds + bb + ldB1);     \
  }
#define BAR                                  \
  asm volatile("" ::: "memory");             \
  __builtin_amdgcn_s_barrier();              \
  asm volatile("" ::: "memory")

  // 32x32 frag read offsets: lane supplies row = base + la, k = cg*8.. (ks via ^32)
  // A row = wr*128 + mf*32 + la  -> line = wr*64 + mf*16 + (la>>1)
  // slot = (l&1)*4 + ks*2 + cg ; addr = line*128 + ((slot^(line&7))<<4)
  const int s0 = ((l & 1) << 2) | cg;
  const int aline0 = wr * 64 + (la >> 1);
  const int bline0 = wc * 32 + (la >> 1);
  const int aoff0 = aline0 * 128 + ((s0 ^ (aline0 & 7)) << 4);          // +mf*2048, ks: ^32
  const int boff0 = 16384 + bline0 * 128 + ((s0 ^ (bline0 & 7)) << 4);  // +nf*2048, ks: ^32

  f32x16 acc[4][2];
#pragma unroll
  for (int mf = 0; mf < 4; ++mf)
#pragma unroll
    for (int nf = 0; nf < 2; ++nf)
#pragma unroll
      for (int e = 0; e < 16; ++e) acc[mf][nf][e] = 0.f;

  // frag sets: index = mf*2+ks (A) / nf*2+ks (B)
  bf16x8 afrX[4], bfrX[4], afrY[4], bfrY[4];

#define CLUSTER1(S)                                                        \
  __builtin_amdgcn_s_setprio(1);                                           \
  _Pragma("unroll") for (int mf = 0; mf < 2; ++mf)                         \
  _Pragma("unroll") for (int nf = 0; nf < 2; ++nf)                         \
  _Pragma("unroll") for (int ks = 0; ks < 2; ++ks)                         \
      acc[mf][nf] = __builtin_amdgcn_mfma_f32_32x32x16_bf16(               \
          afr##S[mf * 2 + ks], bfr##S[nf * 2 + ks], acc[mf][nf], 0, 0, 0); \
  __builtin_amdgcn_s_setprio(0)
#define CLUSTER2(S)                                                        \
  __builtin_amdgcn_s_setprio(1);                                           \
  _Pragma("unroll") for (int mf = 0; mf < 2; ++mf)                         \
  _Pragma("unroll") for (int nf = 0; nf < 2; ++nf)                         \
  _Pragma("unroll") for (int ks = 0; ks < 2; ++ks)                         \
      acc[mf + 2][nf] = __builtin_amdgcn_mfma_f32_32x32x16_bf16(           \
          afr2[mf * 2 + ks], bfr##S[nf * 2 + ks], acc[mf + 2][nf], 0, 0, 0); \
  __builtin_amdgcn_s_setprio(0)

// Iter kt (set S current, R next): tiles kt and kt+1 are published at entry.
#define BODY(kt, S, R)                                                     \
  {                                                                        \
    if ((kt) + 3 < T) STAGE((kt) + 3);                                     \
    const int bbc = ((kt) & 3) * 32768;                                    \
    const int nx = ((kt) + 1 < T) ? (kt) + 1 : (kt);                       \
    const int bbn = (nx & 3) * 32768;                                      \
    bf16x8 afr2[4];                                                        \
    afr2[0] = *(const bf16x8*)(lds + (bbc + aoff0 + 2 * 2048));            \
    afr2[1] = *(const bf16x8*)(lds + ((bbc + aoff0 + 2 * 2048) ^ 32));     \
    afr2[2] = *(const bf16x8*)(lds + (bbc + aoff0 + 3 * 2048));            \
    afr2[3] = *(const bf16x8*)(lds + ((bbc + aoff0 + 3 * 2048) ^ 32));     \
    CLUSTER1(S);                                                           \
    bfr##R[0] = *(const bf16x8*)(lds + (bbn + boff0));                     \
    bfr##R[1] = *(const bf16x8*)(lds + ((bbn + boff0) ^ 32));              \
    bfr##R[2] = *(const bf16x8*)(lds + (bbn + boff0 + 2048));              \
    bfr##R[3] = *(const bf16x8*)(lds + ((bbn + boff0 + 2048) ^ 32));       \
    CLUSTER2(S);                                                           \
    afr##R[0] = *(const bf16x8*)(lds + (bbn + aoff0));                     \
    afr##R[1] = *(const bf16x8*)(lds + ((bbn + aoff0) ^ 32));              \
    afr##R[2] = *(const bf16x8*)(lds + (bbn + aoff0 + 2048));              \
    afr##R[3] = *(const bf16x8*)(lds + ((bbn + aoff0 + 2048) ^ 32));       \
    if ((kt) + 3 < T) {                                                    \
      asm volatile("s_waitcnt vmcnt(4)" ::: "memory");                     \
    } else {                                                               \
      asm volatile("s_waitcnt vmcnt(0)" ::: "memory");                     \
    }                                                                      \
    BAR;                                                                   \
  }

  // prologue: stage 0,1,2; vmcnt(4) -> tiles 0,1 landed; barrier publishes.
  STAGE(0); STAGE(1); STAGE(2);
  asm volatile("s_waitcnt vmcnt(4)" ::: "memory");
  BAR;
  bfrX[0] = *(const bf16x8*)(lds + boff0);
  bfrX[1] = *(const bf16x8*)(lds + (boff0 ^ 32));
  bfrX[2] = *(const bf16x8*)(lds + (boff0 + 2048));
  bfrX[3] = *(const bf16x8*)(lds + ((boff0 + 2048) ^ 32));
  afrX[0] = *(const bf16x8*)(lds + aoff0);
  afrX[1] = *(const bf16x8*)(lds + (aoff0 ^ 32));
  afrX[2] = *(const bf16x8*)(lds + (aoff0 + 2048));
  afrX[3] = *(const bf16x8*)(lds + ((aoff0 + 2048) ^ 32));

  for (int i = 0; i < T / 2; ++i) {
    BODY(2 * i, X, Y);
    BODY(2 * i + 1, Y, X);
  }
#undef STAGE
#undef BAR
#undef CLUSTER1
#undef CLUSTER2
#undef BODY

  // C/D layout (32x32, verified m74/m101): col = la, row = (reg&3)+8*(reg>>2)+4*cg
  const int rowb = bm * 256 + wr * 128 + cg * 4;
  const int col0 = bn * 256 + wc * 64 + la;
  if (OUT_BF16) {
    u16* Cc = (u16*)C;
#pragma unroll
    for (int mf = 0; mf < 4; ++mf)
#pragma unroll
      for (int nf = 0; nf < 2; ++nf)
#pragma unroll
        for (int reg = 0; reg < 16; ++reg) {
          const long row = rowb + mf * 32 + (reg & 3) + ((reg >> 2) << 3);
          Cc[row * N + col0 + nf * 32] = f2bf(acc[mf][nf][reg]);
        }
  } else {
    float* Cf = (float*)C;
    const float bv0 = bias[col0], bv1 = bias[col0 + 32];
#pragma unroll
    for (int mf = 0; mf < 4; ++mf)
#pragma unroll
      for (int reg = 0; reg < 16; ++reg) {
        const long row = rowb + mf * 32 + (reg & 3) + ((reg >> 2) << 3);
        Cf[row * N + col0] = acc[mf][0][reg] + bv0;
        Cf[row * N + col0 + 32] = acc[mf][1][reg] + bv1;
      }
  }
}

// ---------------- fused attention ----------------
__global__ __launch_bounds__(256) void attn_kernel(
    const u16* __restrict__ qkv,        // [B*49, 2304] bf16
    const float* __restrict__ prev,     // [B,12,49,49]
    const float* __restrict__ biasM,    // [12,49*49]
    float* __restrict__ prev_out,       // [B,12,49,49]
    u16* __restrict__ attn_out) {       // [B*49, 768] bf16
  __shared__ u16 Qs[64][72];   // aliased as Ps after QK^T
  __shared__ u16 Ks[64][72];
  __shared__ u16 VTs[64][72];
  __shared__ float SB[2432];   // prev+bias, then scores

  const int bh = blockIdx.x;
  const int b = bh / 12, h = bh % 12;
  const int t = threadIdx.x, w = t >> 6, l = t & 63, lr = l & 15, lhi = l >> 4;

  const u16* base = qkv + (long)(b * 49) * 2304 + h * 64;
  for (int idx = t; idx < 49 * 16; idx += 256) {
    const int n = idx >> 4, c4 = (idx & 15) << 2;
    const u16* rp = base + (long)n * 2304;
    ushort4 qv = *(const ushort4*)(rp + c4);
    ushort4 kv = *(const ushort4*)(rp + 768 + c4);
    ushort4 vv = *(const ushort4*)(rp + 1536 + c4);
    *(ushort4*)&Qs[n][c4] = qv;
    *(ushort4*)&Ks[n][c4] = kv;
    VTs[c4 + 0][n] = vv.x;
    VTs[c4 + 1][n] = vv.y;
    VTs[c4 + 2][n] = vv.z;
    VTs[c4 + 3][n] = vv.w;
  }
  for (int idx = t; idx < 1024; idx += 256) {
    const int j = idx & 15;
    if (j) VTs[idx >> 4][48 + j] = 0;
  }
  {
    const float* pv = prev + (long)bh * 2401;
    const float* bm = biasM + h * 2401;
    for (int i = t; i < 2401; i += 256) SB[i] = pv[i] + bm[i];
  }
  __syncthreads();

  bf16x8 af0 = *(const bf16x8*)&Qs[16 * w + lr][lhi * 8];
  bf16x8 af1 = *(const bf16x8*)&Qs[16 * w + lr][32 + lhi * 8];
  f32x4 sacc[4];
#pragma unroll
  for (int tc = 0; tc < 4; ++tc) {
    sacc[tc] = (f32x4){0.f, 0.f, 0.f, 0.f};
    bf16x8 b0 = *(const bf16x8*)&Ks[16 * tc + lr][lhi * 8];
    bf16x8 b1 = *(const bf16x8*)&Ks[16 * tc + lr][32 + lhi * 8];
    sacc[tc] = __builtin_amdgcn_mfma_f32_16x16x32_bf16(af0, b0, sacc[tc], 0, 0, 0);
    sacc[tc] = __builtin_amdgcn_mfma_f32_16x16x32_bf16(af1, b1, sacc[tc], 0, 0, 0);
  }

  u16 (*Ps)[72] = Qs;
  const int nrow0 = 16 * w + 4 * lhi;
  float rs[4];
#pragma unroll
  for (int r = 0; r < 4; ++r) {
    const int row = nrow0 + r;
    const bool rv = row < 49;
    float sv[4];
#pragma unroll
    for (int tc = 0; tc < 4; ++tc) {
      const int col = 16 * tc + lr;
      const bool valid = rv && (col < 49);
      const int sidx = (row < 49 ? row : 48) * 49 + (col < 49 ? col : 48);
      const float pb = SB[sidx];
      const float s = sacc[tc][r] * 0.125f + pb;
      if (valid) SB[sidx] = s;
      sv[tc] = valid ? s : -INFINITY;
    }
    float mx = fmaxf(fmaxf(sv[0], sv[1]), fmaxf(sv[2], sv[3]));
#pragma unroll
    for (int off = 8; off; off >>= 1) mx = fmaxf(mx, __shfl_xor(mx, off, 16));
    float e[4], sum = 0.f;
#pragma unroll
    for (int tc = 0; tc < 4; ++tc) {
      e[tc] = __expf(sv[tc] - mx);
      sum += e[tc];
    }
#pragma unroll
    for (int off = 8; off; off >>= 1) sum += __shfl_xor(sum, off, 16);
    rs[r] = 1.0f / sum;
#pragma unroll
    for (int tc = 0; tc < 4; ++tc)
      Ps[row][16 * tc + lr] = rv ? f2bf(e[tc]) : (u16)0;
  }
  __syncthreads();

  bf16x8 pf0 = *(const bf16x8*)&Ps[16 * w + lr][lhi * 8];
  bf16x8 pf1 = *(const bf16x8*)&Ps[16 * w + lr][32 + lhi * 8];
  f32x4 oacc[4];
#pragma unroll
  for (int dc = 0; dc < 4; ++dc) {
    oacc[dc] = (f32x4){0.f, 0.f, 0.f, 0.f};
    bf16x8 v0 = *(const bf16x8*)&VTs[16 * dc + lr][lhi * 8];
    bf16x8 v1 = *(const bf16x8*)&VTs[16 * dc + lr][32 + lhi * 8];
    oacc[dc] = __builtin_amdgcn_mfma_f32_16x16x32_bf16(pf0, v0, oacc[dc], 0, 0, 0);
    oacc[dc] = __builtin_amdgcn_mfma_f32_16x16x32_bf16(pf1, v1, oacc[dc], 0, 0, 0);
  }
  u16* ob = attn_out + (long)(b * 49) * 768 + h * 64;
#pragma unroll
  for (int r = 0; r < 4; ++r) {
    const int row = nrow0 + r;
    if (row < 49) {
#pragma unroll
      for (int dc = 0; dc < 4; ++dc)
        ob[(long)row * 768 + 16 * dc + lr] = f2bf(oacc[dc][r] * rs[r]);
    }
  }

  {
    float* pout = prev_out + (long)bh * 2401;
    for (int i = t; i < 2401; i += 256) pout[i] = SB[i];
  }
}

// ---------------- launch ----------------
extern "C" void kernel_launch(void* const* d_in, const int* in_sizes, int n_in,
                              void* d_out, int out_size, void* d_ws, size_t ws_size,
                              hipStream_t stream) {
  const float* x = (const float*)d_in[0];
  const float* prev = (const float*)d_in[1];
  const float* qkv_w = (const float*)d_in[2];
  const float* proj_w = (const float*)d_in[3];
  const float* proj_b = (const float*)d_in[4];
  const float* bias_table = (const float*)d_in[5];
  const int* rel_idx = (const int*)d_in[6];

  const int B = in_sizes[0] / (49 * 768);  // 1024
  const int M = B * 49;                    // 50176 = 196*256

  float* out0 = (float*)d_out;             // [M,768]
  float* out1 = out0 + (size_t)M * 768;    // [B,12,49,49]

  char* ws = (char*)d_ws;
  u16* xbf = (u16*)ws;                                     // M*768 bf16 (reused as attn_out)
  u16* qkvbf = (u16*)(ws + (size_t)M * 768 * 2);           // M*2304 bf16
  u16* qkvwT = (u16*)(ws + (size_t)M * 768 * 2 + (size_t)M * 2304 * 2);  // [2304,768]
  u16* projwT = qkvwT + 2304 * 768;                        // [768,768]
  float* biasM = (float*)(projwT + 768 * 768);             // [12,2401]

  bias_pre<<<(12 * 2401 + 255) / 256, 256, 0, stream>>>(bias_table, rel_idx, biasM);
  cvt_bf16<<<2048, 256, 0, stream>>>(x, xbf, M * 768 / 4);
  cvtT_bf16<<<(2304 * 768 + 255) / 256, 256, 0, stream>>>(qkv_w, qkvwT, 768, 2304);
  cvtT_bf16<<<(768 * 768 + 255) / 256, 256, 0, stream>>>(proj_w, projwT, 768, 768);

  gemm256<true><<<(M / 256) * (2304 / 256), 512, 0, stream>>>(
      xbf, qkvwT, qkvbf, nullptr, M, 2304, 768, 2304 / 256);

  attn_kernel<<<B * 12, 256, 0, stream>>>(qkvbf, prev, biasM, out1, xbf);

  gemm256<false><<<(M / 256) * (768 / 256), 512, 0, stream>>>(
      xbf, projwT, out0, proj_b, M, 768, 768, 768 / 256);
}